// Round 7
// baseline (335.223 us; speedup 1.0000x reference)
//
#include <hip/hip_runtime.h>

// B=16, NQ=NK=784, D_MODEL=512, H=8, DK=DV=64
#define SZX ((size_t)12544 * 512)   // elements of one [B*784, 512] matrix
#define WSEG ((size_t)262144)       // one 512x512 weight

typedef __attribute__((ext_vector_type(8))) short short8;
typedef __attribute__((ext_vector_type(4))) short short4s;
typedef __attribute__((ext_vector_type(4))) float floatx4;

typedef const __attribute__((address_space(1))) void* gas_cvp;
typedef __attribute__((address_space(3))) void* las_vp;

__device__ __forceinline__ void gl_lds16(const void* g, void* l) {
    __builtin_amdgcn_global_load_lds((gas_cvp)g, (las_vp)l, 16, 0, 0);
}

__device__ __forceinline__ unsigned short f2bf(float f) {
    unsigned int u = __float_as_uint(f);
    u += 0x7fffu + ((u >> 16) & 1u);   // RNE
    return (unsigned short)(u >> 16);
}

__device__ __forceinline__ short8 cvt8(floatx4 a, floatx4 b) {
    short8 r;
    r[0] = (short)f2bf(a[0]); r[1] = (short)f2bf(a[1]);
    r[2] = (short)f2bf(a[2]); r[3] = (short)f2bf(a[3]);
    r[4] = (short)f2bf(b[0]); r[5] = (short)f2bf(b[1]);
    r[6] = (short)f2bf(b[2]); r[7] = (short)f2bf(b[3]);
    return r;
}

__device__ __forceinline__ short8 lds_read8(const unsigned short* p) {
    // p is 8B-aligned (not 16B) — two b64 reads
    short4s a = *(const short4s*)p;
    short4s b = *(const short4s*)(p + 4);
    return __builtin_shufflevector(a, b, 0, 1, 2, 3, 4, 5, 6, 7);
}

#define MFMA16(a, b, c) __builtin_amdgcn_mfma_f32_16x16x32_bf16(a, b, c, 0, 0, 0)

// ---------------- weight transpose + convert: Wt[o][i] = bf16(W[i][o]) ------------
__global__ void transpose_cvt(const float* __restrict__ W0, const float* __restrict__ W1,
                              const float* __restrict__ W2, const float* __restrict__ W3,
                              unsigned short* __restrict__ out) {
    __shared__ float tile[32][33];
    const float* W = blockIdx.z == 0 ? W0 : blockIdx.z == 1 ? W1 : blockIdx.z == 2 ? W2 : W3;
    unsigned short* O = out + (size_t)blockIdx.z * WSEG;
    int x = blockIdx.x * 32 + threadIdx.x;
    int y0 = blockIdx.y * 32;
    for (int k = threadIdx.y; k < 32; k += 8)
        tile[k][threadIdx.x] = W[(size_t)(y0 + k) * 512 + x];
    __syncthreads();
    int xo = blockIdx.y * 32 + threadIdx.x;
    int yo0 = blockIdx.x * 32;
    for (int k = threadIdx.y; k < 32; k += 8)
        O[(size_t)(yo0 + k) * 512 + xo] = f2bf(tile[threadIdx.x][k]);
}

// ---------------- merged QKV projection GEMM (128x128 tiles), f32 X fused ---------
// v7: cvt3 eliminated. X (queries/keys/values) is staged DIRECTLY from f32 via
// global_load_lds into a 16KB f32 LDS tile; f32->bf16 (same RNE as cvt3 did, so
// results are bit-identical) happens at fragment-read time, hidden under MFMA
// (m114 VALU/MFMA overlap). The f32 tile's 128B row stride would be a 16-way
// bank conflict, so granule index is XOR-swizzled: linear DMA dest +
// inverse-swizzled SOURCE addr + swizzled read (rule #21), kp ^= row&7 —
// bijective within the row's 8x16B granules, conflicts drop to 2-way (free).
// W side (pre-transposed bf16) staged as before.
// z=0: Qb[row][512] = Xq @ Wtq^T + bq   (X = A, tm=bx; W = B, tn=by)
// z=1: Kb[row][512]
// z=2: Vt[(b*8+h)*64+d][n] swapped: A=Wtv (tm=by), B=Xv (tn=bx)
__global__ __launch_bounds__(256) void gemm_qkv(
    const float* __restrict__ Xq, const float* __restrict__ Xk,
    const float* __restrict__ Xv, const unsigned short* __restrict__ Wt,
    const float* __restrict__ bq, const float* __restrict__ bk, const float* __restrict__ bv,
    unsigned short* __restrict__ Qb, unsigned short* __restrict__ Kb,
    unsigned short* __restrict__ Vtb)
{
    __shared__ float Xls[128 * 32];            // 16KB f32 X-tile (granule-swizzled)
    __shared__ unsigned short Wls[128 * 32];   // 8KB bf16 W-tile
    int z = blockIdx.z;
    const float* X = z == 0 ? Xq : z == 1 ? Xk : Xv;
    const unsigned short* Wz = Wt + (size_t)z * WSEG;
    const float* bias = z == 0 ? bq : z == 1 ? bk : bv;

    int tid = threadIdx.x;
    int lane = tid & 63, wave = tid >> 6;
    int wm = wave & 1, wn = wave >> 1;
    int c16 = lane & 15, g = lane >> 4;

    // X-tile rows always follow blockIdx.x; W-tile rows always follow blockIdx.y
    const float* Xbase = X + (size_t)blockIdx.x * 128 * 512;
    const unsigned short* Wbase = Wz + (size_t)blockIdx.y * 128 * 512;
    int tm = (z < 2) ? blockIdx.x : blockIdx.y;
    int tn = (z < 2) ? blockIdx.y : blockIdx.x;
    // wave-select for fragment rows: X is A for z<2 (use wm), B for z=2 (use wn)
    int wx = (z < 2) ? wm : wn;
    int ww = (z < 2) ? wn : wm;

    floatx4 acc[4][4];
#pragma unroll
    for (int i = 0; i < 4; i++)
#pragma unroll
        for (int j = 0; j < 4; j++) acc[i][j] = (floatx4){0.f, 0.f, 0.f, 0.f};

    for (int kb = 0; kb < 16; ++kb) {
        int k0 = kb * 32;
        // stage X f32: 128 rows x 32 cols = 16KB, 4 passes of 256 lanes x 16B.
        // dest granule kp holds source granule kp^(row&7)  (inverse-swz source)
#pragma unroll
        for (int rep = 0; rep < 4; ++rep) {
            int slot = rep * 256 + tid;
            int row = slot >> 3, kp = slot & 7;
            int src = kp ^ (row & 7);
            gl_lds16(Xbase + (size_t)row * 512 + k0 + src * 4, &Xls[slot * 4]);
        }
        // stage W bf16: 2 passes as before
#pragma unroll
        for (int rep = 0; rep < 2; ++rep) {
            int slot = rep * 256 + tid;
            int row = slot >> 2, kp = slot & 3;
            gl_lds16(Wbase + (size_t)row * 512 + k0 + kp * 8, &Wls[slot * 8]);
        }
        __syncthreads();

        short8 xf[4], wf[4];
#pragma unroll
        for (int i = 0; i < 4; i++) {
            int row = wx * 64 + i * 16 + c16;
            int sw = row & 7;
            floatx4 a = *(const floatx4*)&Xls[row * 32 + ((2 * g + 0) ^ sw) * 4];
            floatx4 b2 = *(const floatx4*)&Xls[row * 32 + ((2 * g + 1) ^ sw) * 4];
            xf[i] = cvt8(a, b2);
        }
#pragma unroll
        for (int j = 0; j < 4; j++)
            wf[j] = *(const short8*)&Wls[(ww * 64 + j * 16 + c16) * 32 + g * 8];

        if (z < 2) {
#pragma unroll
            for (int i = 0; i < 4; i++)
#pragma unroll
                for (int j = 0; j < 4; j++)
                    acc[i][j] = MFMA16(xf[i], wf[j], acc[i][j]);
        } else {
#pragma unroll
            for (int i = 0; i < 4; i++)
#pragma unroll
                for (int j = 0; j < 4; j++)
                    acc[i][j] = MFMA16(wf[i], xf[j], acc[i][j]);
        }
        __syncthreads();
    }

#pragma unroll
    for (int j = 0; j < 4; j++) {
        int n = tn * 128 + wn * 64 + j * 16 + c16;
        int bi = n / 784, nn = n - bi * 784;         // z==2 only
        float bvn = (z < 2) ? bias[n] : 0.f;
#pragma unroll
        for (int i = 0; i < 4; i++) {
#pragma unroll
            for (int r4 = 0; r4 < 4; r4++) {
                int m = tm * 128 + wm * 64 + i * 16 + g * 4 + r4;
                float v = acc[i][j][r4] + ((z < 2) ? bvn : bias[m]);
                if (z == 0)      Qb[(size_t)m * 512 + n] = f2bf(v);
                else if (z == 1) Kb[(size_t)m * 512 + n] = f2bf(v);
                else {
                    int h = m >> 6, d = m & 63;
                    Vtb[(((size_t)bi * 8 + h) * 64 + d) * 784 + nn] = f2bf(v);
                }
            }
        }
    }
}

// ---------------- output projection, swapped (64x128 tiles): out[b][c][q] f32 -----
// A = Wto [512 out][512 in]; B = ctx [12544][512]
__global__ __launch_bounds__(256) void gemm_out(
    const unsigned short* __restrict__ Wto, const unsigned short* __restrict__ ctx,
    const float* __restrict__ bo, float* __restrict__ out)
{
    __shared__ unsigned short Als[64 * 32];
    __shared__ unsigned short Bls[128 * 32];
    int tid = threadIdx.x;
    int lane = tid & 63, wn = tid >> 6;
    int c16 = lane & 15, g = lane >> 4;
    int tm = blockIdx.x, tn = blockIdx.y;

    const unsigned short* Abase = Wto + (size_t)tm * 64 * 512;
    const unsigned short* Bbase = ctx + (size_t)tn * 128 * 512;

    floatx4 acc[4][2];
#pragma unroll
    for (int i = 0; i < 4; i++)
#pragma unroll
        for (int j = 0; j < 2; j++) acc[i][j] = (floatx4){0.f, 0.f, 0.f, 0.f};

    for (int kb = 0; kb < 16; ++kb) {
        int k0 = kb * 32;
        {
            int row = tid >> 2, kp = tid & 3;
            gl_lds16(Abase + (size_t)row * 512 + k0 + kp * 8, &Als[tid * 8]);
        }
#pragma unroll
        for (int rep = 0; rep < 2; ++rep) {
            int slot = rep * 256 + tid;
            int row = slot >> 2, kp = slot & 3;
            gl_lds16(Bbase + (size_t)row * 512 + k0 + kp * 8, &Bls[slot * 8]);
        }
        __syncthreads();
        short8 af[4], bfr[2];
#pragma unroll
        for (int i = 0; i < 4; i++)
            af[i] = *(const short8*)&Als[(i * 16 + c16) * 32 + g * 8];
#pragma unroll
        for (int j = 0; j < 2; j++)
            bfr[j] = *(const short8*)&Bls[(wn * 32 + j * 16 + c16) * 32 + g * 8];
#pragma unroll
        for (int i = 0; i < 4; i++)
#pragma unroll
            for (int j = 0; j < 2; j++)
                acc[i][j] = MFMA16(af[i], bfr[j], acc[i][j]);
        __syncthreads();
    }

#pragma unroll
    for (int j = 0; j < 2; j++) {
        int n = tn * 128 + wn * 32 + j * 16 + c16;
        int bi = n / 784, q = n - bi * 784;
#pragma unroll
        for (int i = 0; i < 4; i++) {
#pragma unroll
            for (int r4 = 0; r4 < 4; r4++) {
                int m = tm * 64 + i * 16 + g * 4 + r4;
                out[((size_t)bi * 512 + m) * 784 + q] = acc[i][j][r4] + bo[m];
            }
        }
    }
}

// ---------------- fused attention, no-max softmax (bounded logits) ----------------
// v7 = EXACT round-0 v0 (97us measured best across 6 variants; all explicit
// corr-scheduling experiments — reg prefetch, coalesced swap, LDS DMA — lost
// to the compiler's own schedule of the scalar gathers).
// block = 256 thr = 4 waves = 4 heads; each wave: 32 q-rows (2 subtiles of 16).
// grid (16 batches, 25 q-tiles, 2 head-halves)
__global__ __launch_bounds__(256) void attn_kernel(
    const unsigned short* __restrict__ Qb,
    const unsigned short* __restrict__ Kb,
    const unsigned short* __restrict__ Vtb,
    const float* __restrict__ corr,
    unsigned short* __restrict__ ctx)
{
    __shared__ unsigned short Plds[2][4][2][16][68];   // [parity][wave][u][row][key(64)+pad4]
    int b = blockIdx.x, qt = blockIdx.y, hh = blockIdx.z;
    int tid = threadIdx.x;
    int lane = tid & 63, w = tid >> 6;
    int h = hh * 4 + w;
    int c16 = lane & 15, g = lane >> 4;
    int q0 = qt * 32;

    short8 aq[2][2];
#pragma unroll
    for (int u = 0; u < 2; ++u) {
        int row = q0 + u * 16 + c16; row = row < 784 ? row : 783;
        const unsigned short* qp = Qb + (size_t)(b * 784 + row) * 512 + h * 64 + g * 8;
        aq[u][0] = *(const short8*)qp;
        aq[u][1] = *(const short8*)(qp + 32);
    }

    floatx4 o[2][4];
    float l[2][4];
#pragma unroll
    for (int u = 0; u < 2; ++u)
#pragma unroll
        for (int nt = 0; nt < 4; nt++) { o[u][nt] = (floatx4){0.f, 0.f, 0.f, 0.f}; l[u][nt] = 0.f; }

    const float* corrb = corr + (size_t)b * 784 * 784;
    int crow[2][4];
#pragma unroll
    for (int u = 0; u < 2; ++u)
#pragma unroll
        for (int r = 0; r < 4; ++r) {
            int rr = q0 + u * 16 + g * 4 + r; rr = rr < 784 ? rr : 783;
            crow[u][r] = rr * 784;
        }

    const unsigned short* Vh = Vtb + ((size_t)(b * 8 + h)) * 64 * 784;
    const unsigned short* Kh = Kb + (size_t)b * 784 * 512 + h * 64;

    for (int it = 0; it < 13; ++it) {
        int k0 = it * 64;
        // QK^T: s[u][t] over 64 keys
        floatx4 s[2][4];
#pragma unroll
        for (int t = 0; t < 4; ++t) {
            int key = k0 + t * 16 + c16; key = key < 784 ? key : 783;
            const unsigned short* kp = Kh + (size_t)key * 512 + g * 8;
            short8 k0f = *(const short8*)kp;
            short8 k1f = *(const short8*)(kp + 32);
#pragma unroll
            for (int u = 0; u < 2; ++u) {
                floatx4 zz = (floatx4){0.f, 0.f, 0.f, 0.f};
                zz = MFMA16(aq[u][0], k0f, zz);
                zz = MFMA16(aq[u][1], k1f, zz);
                s[u][t] = zz;
            }
        }
        // p = exp(s/8 + corr)  (no max: logits bounded by ~6)
        unsigned short* pbase = &Plds[it & 1][w][0][0][0];
#pragma unroll
        for (int u = 0; u < 2; ++u)
#pragma unroll
            for (int t = 0; t < 4; ++t) {
                int key = k0 + t * 16 + c16;
                bool valid = key < 784;
                int kc = valid ? key : 783;
#pragma unroll
                for (int r = 0; r < 4; ++r) {
                    float cv = corrb[crow[u][r] + kc];
                    float sv = fmaf(s[u][t][r], 0.125f, cv);
                    float pv = valid ? __expf(sv) : 0.f;
                    l[u][r] += pv;
                    pbase[(u * 16 + g * 4 + r) * 68 + t * 16 + c16] = f2bf(pv);
                }
            }
        // P·V
#pragma unroll
        for (int u = 0; u < 2; ++u) {
            const unsigned short* pr = &Plds[it & 1][w][u][c16][0];
            short8 pa0 = lds_read8(pr + g * 8);
            short8 pa1 = lds_read8(pr + 32 + g * 8);
#pragma unroll
            for (int nt = 0; nt < 4; ++nt) {
                int d = nt * 16 + c16;
                const unsigned short* vp = Vh + (size_t)d * 784 + k0 + g * 8;
                short8 v0 = *(const short8*)vp;
                short8 v1 = *(const short8*)(vp + 32);
                o[u][nt] = MFMA16(pa0, v0, o[u][nt]);
                o[u][nt] = MFMA16(pa1, v1, o[u][nt]);
            }
        }
    }

    // normalize and store
#pragma unroll
    for (int u = 0; u < 2; ++u)
#pragma unroll
        for (int r = 0; r < 4; ++r) {
            float lv = l[u][r];
            lv += __shfl_xor(lv, 1);
            lv += __shfl_xor(lv, 2);
            lv += __shfl_xor(lv, 4);
            lv += __shfl_xor(lv, 8);
            l[u][r] = 1.0f / lv;
        }
#pragma unroll
    for (int u = 0; u < 2; ++u)
#pragma unroll
        for (int r = 0; r < 4; ++r) {
            int row = q0 + u * 16 + g * 4 + r;
            if (row < 784) {
#pragma unroll
                for (int nt = 0; nt < 4; ++nt)
                    ctx[(size_t)(b * 784 + row) * 512 + h * 64 + nt * 16 + c16] =
                        f2bf(o[u][nt][r] * l[u][r]);
            }
        }
}

extern "C" void kernel_launch(void* const* d_in, const int* in_sizes, int n_in,
                              void* d_out, int out_size, void* d_ws, size_t ws_size,
                              hipStream_t stream) {
    (void)in_sizes; (void)n_in; (void)out_size; (void)ws_size;
    const float* queries = (const float*)d_in[0];
    const float* keys    = (const float*)d_in[1];
    const float* values  = (const float*)d_in[2];
    const float* corr    = (const float*)d_in[3];
    const float* Wq = (const float*)d_in[4];
    const float* bq = (const float*)d_in[5];
    const float* Wk = (const float*)d_in[6];
    const float* bk = (const float*)d_in[7];
    const float* Wv = (const float*)d_in[8];
    const float* bv = (const float*)d_in[9];
    const float* Wo = (const float*)d_in[10];
    const float* bo = (const float*)d_in[11];

    // workspace: Qb, Kb, Vtb, ctx (bf16, SZX each) + Wt (4 x WSEG bf16) = 53.5 MB
    // (old layout needed >=66 MB and passed, so this always fits)
    unsigned short* Qb  = (unsigned short*)d_ws;
    unsigned short* Kb  = Qb + SZX;
    unsigned short* Vtb = Kb + SZX;
    unsigned short* ctx = Vtb + SZX;
    unsigned short* Wt  = ctx + SZX;

    transpose_cvt<<<dim3(16, 16, 4), dim3(32, 8), 0, stream>>>(Wq, Wk, Wv, Wo, Wt);
    gemm_qkv<<<dim3(98, 4, 3), 256, 0, stream>>>(queries, keys, values, Wt,
                                                 bq, bk, bv, Qb, Kb, Vtb);
    attn_kernel<<<dim3(16, 25, 2), 256, 0, stream>>>(Qb, Kb, Vtb, corr, ctx);
    gemm_out<<<dim3(8, 98), 256, 0, stream>>>(Wt + 3 * WSEG, ctx, bo, (float*)d_out);
}

// Round 8
// 322.376 us; speedup vs baseline: 1.0399x; 1.0399x over previous
//
#include <hip/hip_runtime.h>

// B=16, NQ=NK=784, D_MODEL=512, H=8, DK=DV=64
#define SZX ((size_t)12544 * 512)   // elements of one [B*784, 512] matrix
#define WSEG ((size_t)262144)       // one 512x512 weight

typedef __attribute__((ext_vector_type(8))) short short8;
typedef __attribute__((ext_vector_type(4))) short short4s;
typedef __attribute__((ext_vector_type(4))) float floatx4;

typedef const __attribute__((address_space(1))) void* gas_cvp;
typedef __attribute__((address_space(3))) void* las_vp;

__device__ __forceinline__ void gl_lds16(const void* g, void* l) {
    __builtin_amdgcn_global_load_lds((gas_cvp)g, (las_vp)l, 16, 0, 0);
}

__device__ __forceinline__ unsigned short f2bf(float f) {
    unsigned int u = __float_as_uint(f);
    u += 0x7fffu + ((u >> 16) & 1u);   // RNE
    return (unsigned short)(u >> 16);
}

__device__ __forceinline__ short8 cvt8(floatx4 a, floatx4 b) {
    short8 r;
    r[0] = (short)f2bf(a[0]); r[1] = (short)f2bf(a[1]);
    r[2] = (short)f2bf(a[2]); r[3] = (short)f2bf(a[3]);
    r[4] = (short)f2bf(b[0]); r[5] = (short)f2bf(b[1]);
    r[6] = (short)f2bf(b[2]); r[7] = (short)f2bf(b[3]);
    return r;
}

__device__ __forceinline__ short8 lds_read8(const unsigned short* p) {
    // p is 8B-aligned (not 16B) — two b64 reads
    short4s a = *(const short4s*)p;
    short4s b = *(const short4s*)(p + 4);
    return __builtin_shufflevector(a, b, 0, 1, 2, 3, 4, 5, 6, 7);
}

#define MFMA16(a, b, c) __builtin_amdgcn_mfma_f32_16x16x32_bf16(a, b, c, 0, 0, 0)

// ---------------- weight transpose + convert: Wt[o][i] = bf16(W[i][o]) ------------
__global__ void transpose_cvt(const float* __restrict__ W0, const float* __restrict__ W1,
                              const float* __restrict__ W2, const float* __restrict__ W3,
                              unsigned short* __restrict__ out) {
    __shared__ float tile[32][33];
    const float* W = blockIdx.z == 0 ? W0 : blockIdx.z == 1 ? W1 : blockIdx.z == 2 ? W2 : W3;
    unsigned short* O = out + (size_t)blockIdx.z * WSEG;
    int x = blockIdx.x * 32 + threadIdx.x;
    int y0 = blockIdx.y * 32;
    for (int k = threadIdx.y; k < 32; k += 8)
        tile[k][threadIdx.x] = W[(size_t)(y0 + k) * 512 + x];
    __syncthreads();
    int xo = blockIdx.y * 32 + threadIdx.x;
    int yo0 = blockIdx.x * 32;
    for (int k = threadIdx.y; k < 32; k += 8)
        O[(size_t)(yo0 + k) * 512 + xo] = f2bf(tile[threadIdx.x][k]);
}

// ---------------- merged QKV projection GEMM, v8 ----------------------------------
// 128x128 tile, BK=64 (8 K-iters, 32 MFMA between barriers — half the drains),
// f32 X staged fused (no cvt3; bit-identical RNE at fragment read).
// NEW vs v7 (per R7 counters: FETCH 158MB = 2x ideal, BANK_CONFLICT 3.6M = 8-way
// on 64B-row W reads, MfmaUtil 5.6%):
//  1. XCD-sibling remap: 1-D grid, the 4 blocks sharing an X row-tile get ids
//     congruent mod 8 -> same XCD under round-robin dispatch -> X fetched from
//     HBM once per XCD instead of 4x.
//  2. Granule XOR-swizzle (rule #21 both-sides): LDS granule gc holds source
//     granule (gc&8)|((gc&7)^(row&7)) (X: 16x16B/row) or gc^(row&7) (W: 8x16B).
//     Linear DMA dest + inverse-swz source + swz read -> all LDS reads 2-way
//     (free, m136). K-order unchanged -> bit-identical output.
// z=0: Qb = Xq @ Wtq^T + bq ; z=1: Kb ; z=2: Vtb swapped (A=Wtv, B=Xv).
__global__ __launch_bounds__(256) void gemm_qkv(
    const float* __restrict__ Xq, const float* __restrict__ Xk,
    const float* __restrict__ Xv, const unsigned short* __restrict__ Wt,
    const float* __restrict__ bq, const float* __restrict__ bk, const float* __restrict__ bv,
    unsigned short* __restrict__ Qb, unsigned short* __restrict__ Kb,
    unsigned short* __restrict__ Vtb)
{
    __shared__ float Xls[128 * 64];            // 32KB f32 X-tile (granule-swizzled)
    __shared__ unsigned short Wls[128 * 64];   // 16KB bf16 W-tile (granule-swizzled)
    int z = blockIdx.z;
    const float* X = z == 0 ? Xq : z == 1 ? Xk : Xv;
    const unsigned short* Wz = Wt + (size_t)z * WSEG;
    const float* bias = z == 0 ? bq : z == 1 ? bk : bv;

    int tid = threadIdx.x;
    int lane = tid & 63, wave = tid >> 6;
    int wm = wave & 1, wn = wave >> 1;
    int c16 = lane & 15, g = lane >> 4;

    // XCD-sibling remap: i98 indexes the X tile (98 of them), i4 the W tile (4).
    // Siblings (same i98, 4 i4 values) have linear ids {j, j+8, j+16, j+24}.
    int G = blockIdx.x;
    int i98, i4;
    if (G < 384) { i98 = (G >> 5) * 8 + (G & 7); i4 = (G >> 3) & 3; }
    else         { int r = G - 384; i98 = 96 + (r & 1); i4 = r >> 1; }

    const float* Xbase = X + (size_t)i98 * 128 * 512;
    const unsigned short* Wbase = Wz + (size_t)i4 * 128 * 512;
    int tm = (z < 2) ? i98 : i4;
    int tn = (z < 2) ? i4 : i98;
    // X is the A-side for z<2 (rows follow wm), B-side for z=2 (rows follow wn)
    int wx = (z < 2) ? wm : wn;
    int ww = (z < 2) ? wn : wm;

    floatx4 acc[4][4];
#pragma unroll
    for (int i = 0; i < 4; i++)
#pragma unroll
        for (int j = 0; j < 4; j++) acc[i][j] = (floatx4){0.f, 0.f, 0.f, 0.f};

    for (int kb = 0; kb < 8; ++kb) {
        int k0 = kb * 64;
        // stage X f32 [128][64]: 8 passes x 256 lanes x 16B; row = 16 granules.
        // dest granule gc holds source granule (gc&8)|((gc&7)^(row&7))
#pragma unroll
        for (int rep = 0; rep < 8; ++rep) {
            int slot = rep * 256 + tid;
            int row = slot >> 4, gc = slot & 15;
            int src = (gc & 8) | ((gc & 7) ^ (row & 7));
            gl_lds16(Xbase + (size_t)row * 512 + k0 + src * 4, &Xls[slot * 4]);
        }
        // stage W bf16 [128][64]: 4 passes; row = 8 granules, src = gc^(row&7)
#pragma unroll
        for (int rep = 0; rep < 4; ++rep) {
            int slot = rep * 256 + tid;
            int row = slot >> 3, gc = slot & 7;
            int src = gc ^ (row & 7);
            gl_lds16(Wbase + (size_t)row * 512 + k0 + src * 8, &Wls[slot * 8]);
        }
        __syncthreads();

#pragma unroll
        for (int kk = 0; kk < 2; ++kk) {
            short8 xf[4], wf[4];
#pragma unroll
            for (int i = 0; i < 4; i++) {
                int row = wx * 64 + i * 16 + c16;
                int sw = row & 7;
                int g0 = kk * 8 + 2 * g;          // logical granule of first f32x4
                int p0 = (g0 & 8) | ((g0 & 7) ^ sw);
                int p1 = ((g0 + 1) & 8) | (((g0 + 1) & 7) ^ sw);
                floatx4 a  = *(const floatx4*)&Xls[row * 64 + p0 * 4];
                floatx4 b2 = *(const floatx4*)&Xls[row * 64 + p1 * 4];
                xf[i] = cvt8(a, b2);
            }
#pragma unroll
            for (int j = 0; j < 4; j++) {
                int row = ww * 64 + j * 16 + c16;
                int gl = kk * 4 + g;              // logical granule (16B = 8 shorts)
                wf[j] = *(const short8*)&Wls[row * 64 + (gl ^ (row & 7)) * 8];
            }
            if (z < 2) {
#pragma unroll
                for (int i = 0; i < 4; i++)
#pragma unroll
                    for (int j = 0; j < 4; j++)
                        acc[i][j] = MFMA16(xf[i], wf[j], acc[i][j]);
            } else {
#pragma unroll
                for (int i = 0; i < 4; i++)
#pragma unroll
                    for (int j = 0; j < 4; j++)
                        acc[i][j] = MFMA16(wf[i], xf[j], acc[i][j]);
            }
        }
        __syncthreads();
    }

#pragma unroll
    for (int j = 0; j < 4; j++) {
        int n = tn * 128 + wn * 64 + j * 16 + c16;
        int bi = n / 784, nn = n - bi * 784;         // z==2 only
        float bvn = (z < 2) ? bias[n] : 0.f;
#pragma unroll
        for (int i = 0; i < 4; i++) {
#pragma unroll
            for (int r4 = 0; r4 < 4; r4++) {
                int m = tm * 128 + wm * 64 + i * 16 + g * 4 + r4;
                float v = acc[i][j][r4] + ((z < 2) ? bvn : bias[m]);
                if (z == 0)      Qb[(size_t)m * 512 + n] = f2bf(v);
                else if (z == 1) Kb[(size_t)m * 512 + n] = f2bf(v);
                else {
                    int h = m >> 6, d = m & 63;
                    Vtb[(((size_t)bi * 8 + h) * 64 + d) * 784 + nn] = f2bf(v);
                }
            }
        }
    }
}

// ---------------- output projection, swapped (64x128 tiles): out[b][c][q] f32 -----
// UNCHANGED from v7 — serves as the in-run control vs gemm_qkv's restructure.
// A = Wto [512 out][512 in]; B = ctx [12544][512]
__global__ __launch_bounds__(256) void gemm_out(
    const unsigned short* __restrict__ Wto, const unsigned short* __restrict__ ctx,
    const float* __restrict__ bo, float* __restrict__ out)
{
    __shared__ unsigned short Als[64 * 32];
    __shared__ unsigned short Bls[128 * 32];
    int tid = threadIdx.x;
    int lane = tid & 63, wn = tid >> 6;
    int c16 = lane & 15, g = lane >> 4;
    int tm = blockIdx.x, tn = blockIdx.y;

    const unsigned short* Abase = Wto + (size_t)tm * 64 * 512;
    const unsigned short* Bbase = ctx + (size_t)tn * 128 * 512;

    floatx4 acc[4][2];
#pragma unroll
    for (int i = 0; i < 4; i++)
#pragma unroll
        for (int j = 0; j < 2; j++) acc[i][j] = (floatx4){0.f, 0.f, 0.f, 0.f};

    for (int kb = 0; kb < 16; ++kb) {
        int k0 = kb * 32;
        {
            int row = tid >> 2, kp = tid & 3;
            gl_lds16(Abase + (size_t)row * 512 + k0 + kp * 8, &Als[tid * 8]);
        }
#pragma unroll
        for (int rep = 0; rep < 2; ++rep) {
            int slot = rep * 256 + tid;
            int row = slot >> 2, kp = slot & 3;
            gl_lds16(Bbase + (size_t)row * 512 + k0 + kp * 8, &Bls[slot * 8]);
        }
        __syncthreads();
        short8 af[4], bfr[2];
#pragma unroll
        for (int i = 0; i < 4; i++)
            af[i] = *(const short8*)&Als[(i * 16 + c16) * 32 + g * 8];
#pragma unroll
        for (int j = 0; j < 2; j++)
            bfr[j] = *(const short8*)&Bls[(wn * 32 + j * 16 + c16) * 32 + g * 8];
#pragma unroll
        for (int i = 0; i < 4; i++)
#pragma unroll
            for (int j = 0; j < 2; j++)
                acc[i][j] = MFMA16(af[i], bfr[j], acc[i][j]);
        __syncthreads();
    }

#pragma unroll
    for (int j = 0; j < 2; j++) {
        int n = tn * 128 + wn * 32 + j * 16 + c16;
        int bi = n / 784, q = n - bi * 784;
#pragma unroll
        for (int i = 0; i < 4; i++) {
#pragma unroll
            for (int r4 = 0; r4 < 4; r4++) {
                int m = tm * 64 + i * 16 + g * 4 + r4;
                out[((size_t)bi * 512 + m) * 784 + q] = acc[i][j][r4] + bo[m];
            }
        }
    }
}

// ---------------- fused attention, no-max softmax (bounded logits) ----------------
// UNCHANGED round-0 v0 (97us measured best across all attn variants).
// block = 256 thr = 4 waves = 4 heads; each wave: 32 q-rows (2 subtiles of 16).
// grid (16 batches, 25 q-tiles, 2 head-halves)
__global__ __launch_bounds__(256) void attn_kernel(
    const unsigned short* __restrict__ Qb,
    const unsigned short* __restrict__ Kb,
    const unsigned short* __restrict__ Vtb,
    const float* __restrict__ corr,
    unsigned short* __restrict__ ctx)
{
    __shared__ unsigned short Plds[2][4][2][16][68];   // [parity][wave][u][row][key(64)+pad4]
    int b = blockIdx.x, qt = blockIdx.y, hh = blockIdx.z;
    int tid = threadIdx.x;
    int lane = tid & 63, w = tid >> 6;
    int h = hh * 4 + w;
    int c16 = lane & 15, g = lane >> 4;
    int q0 = qt * 32;

    short8 aq[2][2];
#pragma unroll
    for (int u = 0; u < 2; ++u) {
        int row = q0 + u * 16 + c16; row = row < 784 ? row : 783;
        const unsigned short* qp = Qb + (size_t)(b * 784 + row) * 512 + h * 64 + g * 8;
        aq[u][0] = *(const short8*)qp;
        aq[u][1] = *(const short8*)(qp + 32);
    }

    floatx4 o[2][4];
    float l[2][4];
#pragma unroll
    for (int u = 0; u < 2; ++u)
#pragma unroll
        for (int nt = 0; nt < 4; nt++) { o[u][nt] = (floatx4){0.f, 0.f, 0.f, 0.f}; l[u][nt] = 0.f; }

    const float* corrb = corr + (size_t)b * 784 * 784;
    int crow[2][4];
#pragma unroll
    for (int u = 0; u < 2; ++u)
#pragma unroll
        for (int r = 0; r < 4; ++r) {
            int rr = q0 + u * 16 + g * 4 + r; rr = rr < 784 ? rr : 783;
            crow[u][r] = rr * 784;
        }

    const unsigned short* Vh = Vtb + ((size_t)(b * 8 + h)) * 64 * 784;
    const unsigned short* Kh = Kb + (size_t)b * 784 * 512 + h * 64;

    for (int it = 0; it < 13; ++it) {
        int k0 = it * 64;
        // QK^T: s[u][t] over 64 keys
        floatx4 s[2][4];
#pragma unroll
        for (int t = 0; t < 4; ++t) {
            int key = k0 + t * 16 + c16; key = key < 784 ? key : 783;
            const unsigned short* kp = Kh + (size_t)key * 512 + g * 8;
            short8 k0f = *(const short8*)kp;
            short8 k1f = *(const short8*)(kp + 32);
#pragma unroll
            for (int u = 0; u < 2; ++u) {
                floatx4 zz = (floatx4){0.f, 0.f, 0.f, 0.f};
                zz = MFMA16(aq[u][0], k0f, zz);
                zz = MFMA16(aq[u][1], k1f, zz);
                s[u][t] = zz;
            }
        }
        // p = exp(s/8 + corr)  (no max: logits bounded by ~6)
        unsigned short* pbase = &Plds[it & 1][w][0][0][0];
#pragma unroll
        for (int u = 0; u < 2; ++u)
#pragma unroll
            for (int t = 0; t < 4; ++t) {
                int key = k0 + t * 16 + c16;
                bool valid = key < 784;
                int kc = valid ? key : 783;
#pragma unroll
                for (int r = 0; r < 4; ++r) {
                    float cv = corrb[crow[u][r] + kc];
                    float sv = fmaf(s[u][t][r], 0.125f, cv);
                    float pv = valid ? __expf(sv) : 0.f;
                    l[u][r] += pv;
                    pbase[(u * 16 + g * 4 + r) * 68 + t * 16 + c16] = f2bf(pv);
                }
            }
        // P·V
#pragma unroll
        for (int u = 0; u < 2; ++u) {
            const unsigned short* pr = &Plds[it & 1][w][u][c16][0];
            short8 pa0 = lds_read8(pr + g * 8);
            short8 pa1 = lds_read8(pr + 32 + g * 8);
#pragma unroll
            for (int nt = 0; nt < 4; ++nt) {
                int d = nt * 16 + c16;
                const unsigned short* vp = Vh + (size_t)d * 784 + k0 + g * 8;
                short8 v0 = *(const short8*)vp;
                short8 v1 = *(const short8*)(vp + 32);
                o[u][nt] = MFMA16(pa0, v0, o[u][nt]);
                o[u][nt] = MFMA16(pa1, v1, o[u][nt]);
            }
        }
    }

    // normalize and store
#pragma unroll
    for (int u = 0; u < 2; ++u)
#pragma unroll
        for (int r = 0; r < 4; ++r) {
            float lv = l[u][r];
            lv += __shfl_xor(lv, 1);
            lv += __shfl_xor(lv, 2);
            lv += __shfl_xor(lv, 4);
            lv += __shfl_xor(lv, 8);
            l[u][r] = 1.0f / lv;
        }
#pragma unroll
    for (int u = 0; u < 2; ++u)
#pragma unroll
        for (int r = 0; r < 4; ++r) {
            int row = q0 + u * 16 + g * 4 + r;
            if (row < 784) {
#pragma unroll
                for (int nt = 0; nt < 4; ++nt)
                    ctx[(size_t)(b * 784 + row) * 512 + h * 64 + nt * 16 + c16] =
                        f2bf(o[u][nt][r] * l[u][r]);
            }
        }
}

extern "C" void kernel_launch(void* const* d_in, const int* in_sizes, int n_in,
                              void* d_out, int out_size, void* d_ws, size_t ws_size,
                              hipStream_t stream) {
    (void)in_sizes; (void)n_in; (void)out_size; (void)ws_size;
    const float* queries = (const float*)d_in[0];
    const float* keys    = (const float*)d_in[1];
    const float* values  = (const float*)d_in[2];
    const float* corr    = (const float*)d_in[3];
    const float* Wq = (const float*)d_in[4];
    const float* bq = (const float*)d_in[5];
    const float* Wk = (const float*)d_in[6];
    const float* bk = (const float*)d_in[7];
    const float* Wv = (const float*)d_in[8];
    const float* bv = (const float*)d_in[9];
    const float* Wo = (const float*)d_in[10];
    const float* bo = (const float*)d_in[11];

    // workspace: Qb, Kb, Vtb, ctx (bf16, SZX each) + Wt (4 x WSEG bf16) = 53.5 MB
    unsigned short* Qb  = (unsigned short*)d_ws;
    unsigned short* Kb  = Qb + SZX;
    unsigned short* Vtb = Kb + SZX;
    unsigned short* ctx = Vtb + SZX;
    unsigned short* Wt  = ctx + SZX;

    transpose_cvt<<<dim3(16, 16, 4), dim3(32, 8), 0, stream>>>(Wq, Wk, Wv, Wo, Wt);
    gemm_qkv<<<dim3(392, 1, 3), 256, 0, stream>>>(queries, keys, values, Wt,
                                                  bq, bk, bv, Qb, Kb, Vtb);
    attn_kernel<<<dim3(16, 25, 2), 256, 0, stream>>>(Qb, Kb, Vtb, corr, ctx);
    gemm_out<<<dim3(8, 98), 256, 0, stream>>>(Wt + 3 * WSEG, ctx, bo, (float*)d_out);
}

// Round 9
// 315.509 us; speedup vs baseline: 1.0625x; 1.0218x over previous
//
#include <hip/hip_runtime.h>

// B=16, NQ=NK=784, D_MODEL=512, H=8, DK=DV=64
#define SZX ((size_t)12544 * 512)   // elements of one [B*784, 512] matrix
#define WSEG ((size_t)262144)       // one 512x512 weight

typedef __attribute__((ext_vector_type(8))) short short8;
typedef __attribute__((ext_vector_type(4))) short short4s;
typedef __attribute__((ext_vector_type(4))) float floatx4;

typedef const __attribute__((address_space(1))) void* gas_cvp;
typedef __attribute__((address_space(3))) void* las_vp;

__device__ __forceinline__ void gl_lds16(const void* g, void* l) {
    __builtin_amdgcn_global_load_lds((gas_cvp)g, (las_vp)l, 16, 0, 0);
}

__device__ __forceinline__ unsigned short f2bf(float f) {
    unsigned int u = __float_as_uint(f);
    u += 0x7fffu + ((u >> 16) & 1u);   // RNE
    return (unsigned short)(u >> 16);
}

__device__ __forceinline__ short8 cvt8(floatx4 a, floatx4 b) {
    short8 r;
    r[0] = (short)f2bf(a[0]); r[1] = (short)f2bf(a[1]);
    r[2] = (short)f2bf(a[2]); r[3] = (short)f2bf(a[3]);
    r[4] = (short)f2bf(b[0]); r[5] = (short)f2bf(b[1]);
    r[6] = (short)f2bf(b[2]); r[7] = (short)f2bf(b[3]);
    return r;
}

__device__ __forceinline__ short8 lds_read8(const unsigned short* p) {
    // p is 8B-aligned (not 16B) — two b64 reads
    short4s a = *(const short4s*)p;
    short4s b = *(const short4s*)(p + 4);
    return __builtin_shufflevector(a, b, 0, 1, 2, 3, 4, 5, 6, 7);
}

#define MFMA16(a, b, c) __builtin_amdgcn_mfma_f32_16x16x32_bf16(a, b, c, 0, 0, 0)

// ---------------- weight transpose + convert: Wt[o][i] = bf16(W[i][o]) ------------
__global__ void transpose_cvt(const float* __restrict__ W0, const float* __restrict__ W1,
                              const float* __restrict__ W2, const float* __restrict__ W3,
                              unsigned short* __restrict__ out) {
    __shared__ float tile[32][33];
    const float* W = blockIdx.z == 0 ? W0 : blockIdx.z == 1 ? W1 : blockIdx.z == 2 ? W2 : W3;
    unsigned short* O = out + (size_t)blockIdx.z * WSEG;
    int x = blockIdx.x * 32 + threadIdx.x;
    int y0 = blockIdx.y * 32;
    for (int k = threadIdx.y; k < 32; k += 8)
        tile[k][threadIdx.x] = W[(size_t)(y0 + k) * 512 + x];
    __syncthreads();
    int xo = blockIdx.y * 32 + threadIdx.x;
    int yo0 = blockIdx.x * 32;
    for (int k = threadIdx.y; k < 32; k += 8)
        O[(size_t)(yo0 + k) * 512 + xo] = f2bf(tile[threadIdx.x][k]);
}

// ---------------- merged QKV projection GEMM, v8 (UNCHANGED — validated R8) -------
// 128x128 tile, BK=64, f32 X staged fused, XCD-sibling remap, granule XOR-swizzle.
// R8 result: dropped out of top-5 (<96us, was 134); total -13us; bit-identical.
__global__ __launch_bounds__(256) void gemm_qkv(
    const float* __restrict__ Xq, const float* __restrict__ Xk,
    const float* __restrict__ Xv, const unsigned short* __restrict__ Wt,
    const float* __restrict__ bq, const float* __restrict__ bk, const float* __restrict__ bv,
    unsigned short* __restrict__ Qb, unsigned short* __restrict__ Kb,
    unsigned short* __restrict__ Vtb)
{
    __shared__ float Xls[128 * 64];            // 32KB f32 X-tile (granule-swizzled)
    __shared__ unsigned short Wls[128 * 64];   // 16KB bf16 W-tile (granule-swizzled)
    int z = blockIdx.z;
    const float* X = z == 0 ? Xq : z == 1 ? Xk : Xv;
    const unsigned short* Wz = Wt + (size_t)z * WSEG;
    const float* bias = z == 0 ? bq : z == 1 ? bk : bv;

    int tid = threadIdx.x;
    int lane = tid & 63, wave = tid >> 6;
    int wm = wave & 1, wn = wave >> 1;
    int c16 = lane & 15, g = lane >> 4;

    // XCD-sibling remap: blocks sharing an X row-tile get ids congruent mod 8.
    int G = blockIdx.x;
    int i98, i4;
    if (G < 384) { i98 = (G >> 5) * 8 + (G & 7); i4 = (G >> 3) & 3; }
    else         { int r = G - 384; i98 = 96 + (r & 1); i4 = r >> 1; }

    const float* Xbase = X + (size_t)i98 * 128 * 512;
    const unsigned short* Wbase = Wz + (size_t)i4 * 128 * 512;
    int tm = (z < 2) ? i98 : i4;
    int tn = (z < 2) ? i4 : i98;
    int wx = (z < 2) ? wm : wn;
    int ww = (z < 2) ? wn : wm;

    floatx4 acc[4][4];
#pragma unroll
    for (int i = 0; i < 4; i++)
#pragma unroll
        for (int j = 0; j < 4; j++) acc[i][j] = (floatx4){0.f, 0.f, 0.f, 0.f};

    for (int kb = 0; kb < 8; ++kb) {
        int k0 = kb * 64;
#pragma unroll
        for (int rep = 0; rep < 8; ++rep) {
            int slot = rep * 256 + tid;
            int row = slot >> 4, gc = slot & 15;
            int src = (gc & 8) | ((gc & 7) ^ (row & 7));
            gl_lds16(Xbase + (size_t)row * 512 + k0 + src * 4, &Xls[slot * 4]);
        }
#pragma unroll
        for (int rep = 0; rep < 4; ++rep) {
            int slot = rep * 256 + tid;
            int row = slot >> 3, gc = slot & 7;
            int src = gc ^ (row & 7);
            gl_lds16(Wbase + (size_t)row * 512 + k0 + src * 8, &Wls[slot * 8]);
        }
        __syncthreads();

#pragma unroll
        for (int kk = 0; kk < 2; ++kk) {
            short8 xf[4], wf[4];
#pragma unroll
            for (int i = 0; i < 4; i++) {
                int row = wx * 64 + i * 16 + c16;
                int sw = row & 7;
                int g0 = kk * 8 + 2 * g;
                int p0 = (g0 & 8) | ((g0 & 7) ^ sw);
                int p1 = ((g0 + 1) & 8) | (((g0 + 1) & 7) ^ sw);
                floatx4 a  = *(const floatx4*)&Xls[row * 64 + p0 * 4];
                floatx4 b2 = *(const floatx4*)&Xls[row * 64 + p1 * 4];
                xf[i] = cvt8(a, b2);
            }
#pragma unroll
            for (int j = 0; j < 4; j++) {
                int row = ww * 64 + j * 16 + c16;
                int gl = kk * 4 + g;
                wf[j] = *(const short8*)&Wls[row * 64 + (gl ^ (row & 7)) * 8];
            }
            if (z < 2) {
#pragma unroll
                for (int i = 0; i < 4; i++)
#pragma unroll
                    for (int j = 0; j < 4; j++)
                        acc[i][j] = MFMA16(xf[i], wf[j], acc[i][j]);
            } else {
#pragma unroll
                for (int i = 0; i < 4; i++)
#pragma unroll
                    for (int j = 0; j < 4; j++)
                        acc[i][j] = MFMA16(wf[i], xf[j], acc[i][j]);
            }
        }
        __syncthreads();
    }

#pragma unroll
    for (int j = 0; j < 4; j++) {
        int n = tn * 128 + wn * 64 + j * 16 + c16;
        int bi = n / 784, nn = n - bi * 784;         // z==2 only
        float bvn = (z < 2) ? bias[n] : 0.f;
#pragma unroll
        for (int i = 0; i < 4; i++) {
#pragma unroll
            for (int r4 = 0; r4 < 4; r4++) {
                int m = tm * 128 + wm * 64 + i * 16 + g * 4 + r4;
                float v = acc[i][j][r4] + ((z < 2) ? bvn : bias[m]);
                if (z == 0)      Qb[(size_t)m * 512 + n] = f2bf(v);
                else if (z == 1) Kb[(size_t)m * 512 + n] = f2bf(v);
                else {
                    int h = m >> 6, d = m & 63;
                    Vtb[(((size_t)bi * 8 + h) * 64 + d) * 784 + nn] = f2bf(v);
                }
            }
        }
    }
}

// ---------------- output projection, v9: the v8 recipe applied --------------------
// out[b][c][q] f32 = Wto @ ctx^T + bo. A = Wto [512][512] bf16 (4 tm tiles of
// 128), B = ctx [12544][512] bf16 (98 tn tiles of 128). Was: 64x128 tile, BK=32,
// 8 MFMA/barrier-pair, un-swizzled 64B-row LDS (8-way conflict), tm-fastest grid
// (8 XCDs each refetching the shared ctx tile). Now: 128x128 tile, BK=64
// (32 MFMA/barrier-pair), granule XOR-swizzle on both tiles (rule #21:
// linear DMA dest + inverse-swz source + swz read), XCD-sibling remap (the 4
// blocks sharing a ctx tile -> ids congruent mod 8 -> same XCD). K-accumulation
// order unchanged -> bit-identical output (absmax tripwire 9.536743e-07).
__global__ __launch_bounds__(256) void gemm_out(
    const unsigned short* __restrict__ Wto, const unsigned short* __restrict__ ctx,
    const float* __restrict__ bo, float* __restrict__ out)
{
    __shared__ unsigned short Als[128 * 64];   // 16KB Wto tile (granule-swizzled)
    __shared__ unsigned short Bls[128 * 64];   // 16KB ctx tile (granule-swizzled)
    int tid = threadIdx.x;
    int lane = tid & 63, wave = tid >> 6;
    int wm = wave & 1, wn = wave >> 1;
    int c16 = lane & 15, g = lane >> 4;

    // XCD-sibling remap: i98 -> ctx tile (tn), i4 -> Wto tile (tm); the 4 blocks
    // sharing a ctx tile have ids {j, j+8, j+16, j+24} -> same XCD mod 8.
    int G = blockIdx.x;
    int i98, i4;
    if (G < 384) { i98 = (G >> 5) * 8 + (G & 7); i4 = (G >> 3) & 3; }
    else         { int r = G - 384; i98 = 96 + (r & 1); i4 = r >> 1; }
    int tm = i4, tn = i98;

    const unsigned short* Abase = Wto + (size_t)tm * 128 * 512;
    const unsigned short* Bbase = ctx + (size_t)tn * 128 * 512;

    floatx4 acc[4][4];
#pragma unroll
    for (int i = 0; i < 4; i++)
#pragma unroll
        for (int j = 0; j < 4; j++) acc[i][j] = (floatx4){0.f, 0.f, 0.f, 0.f};

    for (int kb = 0; kb < 8; ++kb) {
        int k0 = kb * 64;
        // stage both bf16 tiles [128][64]: 4 passes x 256 lanes x 16B each;
        // row = 8 granules of 8 shorts; dest granule gc <- source gc^(row&7)
#pragma unroll
        for (int rep = 0; rep < 4; ++rep) {
            int slot = rep * 256 + tid;
            int row = slot >> 3, gc = slot & 7;
            int src = gc ^ (row & 7);
            gl_lds16(Abase + (size_t)row * 512 + k0 + src * 8, &Als[slot * 8]);
            gl_lds16(Bbase + (size_t)row * 512 + k0 + src * 8, &Bls[slot * 8]);
        }
        __syncthreads();

#pragma unroll
        for (int kk = 0; kk < 2; ++kk) {
            short8 af[4], bfr[4];
#pragma unroll
            for (int i = 0; i < 4; i++) {
                int row = wm * 64 + i * 16 + c16;
                int gl = kk * 4 + g;
                af[i] = *(const short8*)&Als[row * 64 + (gl ^ (row & 7)) * 8];
            }
#pragma unroll
            for (int j = 0; j < 4; j++) {
                int row = wn * 64 + j * 16 + c16;
                int gl = kk * 4 + g;
                bfr[j] = *(const short8*)&Bls[row * 64 + (gl ^ (row & 7)) * 8];
            }
#pragma unroll
            for (int i = 0; i < 4; i++)
#pragma unroll
                for (int j = 0; j < 4; j++)
                    acc[i][j] = MFMA16(af[i], bfr[j], acc[i][j]);
        }
        __syncthreads();
    }

#pragma unroll
    for (int j = 0; j < 4; j++) {
        int n = tn * 128 + wn * 64 + j * 16 + c16;
        int bi = n / 784, q = n - bi * 784;
#pragma unroll
        for (int i = 0; i < 4; i++) {
#pragma unroll
            for (int r4 = 0; r4 < 4; r4++) {
                int m = tm * 128 + wm * 64 + i * 16 + g * 4 + r4;
                out[((size_t)bi * 512 + m) * 784 + q] = acc[i][j][r4] + bo[m];
            }
        }
    }
}

// ---------------- fused attention, no-max softmax (bounded logits) ----------------
// UNCHANGED round-0 v0 (97us measured best across all attn variants).
// block = 256 thr = 4 waves = 4 heads; each wave: 32 q-rows (2 subtiles of 16).
// grid (16 batches, 25 q-tiles, 2 head-halves)
__global__ __launch_bounds__(256) void attn_kernel(
    const unsigned short* __restrict__ Qb,
    const unsigned short* __restrict__ Kb,
    const unsigned short* __restrict__ Vtb,
    const float* __restrict__ corr,
    unsigned short* __restrict__ ctx)
{
    __shared__ unsigned short Plds[2][4][2][16][68];   // [parity][wave][u][row][key(64)+pad4]
    int b = blockIdx.x, qt = blockIdx.y, hh = blockIdx.z;
    int tid = threadIdx.x;
    int lane = tid & 63, w = tid >> 6;
    int h = hh * 4 + w;
    int c16 = lane & 15, g = lane >> 4;
    int q0 = qt * 32;

    short8 aq[2][2];
#pragma unroll
    for (int u = 0; u < 2; ++u) {
        int row = q0 + u * 16 + c16; row = row < 784 ? row : 783;
        const unsigned short* qp = Qb + (size_t)(b * 784 + row) * 512 + h * 64 + g * 8;
        aq[u][0] = *(const short8*)qp;
        aq[u][1] = *(const short8*)(qp + 32);
    }

    floatx4 o[2][4];
    float l[2][4];
#pragma unroll
    for (int u = 0; u < 2; ++u)
#pragma unroll
        for (int nt = 0; nt < 4; nt++) { o[u][nt] = (floatx4){0.f, 0.f, 0.f, 0.f}; l[u][nt] = 0.f; }

    const float* corrb = corr + (size_t)b * 784 * 784;
    int crow[2][4];
#pragma unroll
    for (int u = 0; u < 2; ++u)
#pragma unroll
        for (int r = 0; r < 4; ++r) {
            int rr = q0 + u * 16 + g * 4 + r; rr = rr < 784 ? rr : 783;
            crow[u][r] = rr * 784;
        }

    const unsigned short* Vh = Vtb + ((size_t)(b * 8 + h)) * 64 * 784;
    const unsigned short* Kh = Kb + (size_t)b * 784 * 512 + h * 64;

    for (int it = 0; it < 13; ++it) {
        int k0 = it * 64;
        // QK^T: s[u][t] over 64 keys
        floatx4 s[2][4];
#pragma unroll
        for (int t = 0; t < 4; ++t) {
            int key = k0 + t * 16 + c16; key = key < 784 ? key : 783;
            const unsigned short* kp = Kh + (size_t)key * 512 + g * 8;
            short8 k0f = *(const short8*)kp;
            short8 k1f = *(const short8*)(kp + 32);
#pragma unroll
            for (int u = 0; u < 2; ++u) {
                floatx4 zz = (floatx4){0.f, 0.f, 0.f, 0.f};
                zz = MFMA16(aq[u][0], k0f, zz);
                zz = MFMA16(aq[u][1], k1f, zz);
                s[u][t] = zz;
            }
        }
        // p = exp(s/8 + corr)  (no max: logits bounded by ~6)
        unsigned short* pbase = &Plds[it & 1][w][0][0][0];
#pragma unroll
        for (int u = 0; u < 2; ++u)
#pragma unroll
            for (int t = 0; t < 4; ++t) {
                int key = k0 + t * 16 + c16;
                bool valid = key < 784;
                int kc = valid ? key : 783;
#pragma unroll
                for (int r = 0; r < 4; ++r) {
                    float cv = corrb[crow[u][r] + kc];
                    float sv = fmaf(s[u][t][r], 0.125f, cv);
                    float pv = valid ? __expf(sv) : 0.f;
                    l[u][r] += pv;
                    pbase[(u * 16 + g * 4 + r) * 68 + t * 16 + c16] = f2bf(pv);
                }
            }
        // P·V
#pragma unroll
        for (int u = 0; u < 2; ++u) {
            const unsigned short* pr = &Plds[it & 1][w][u][c16][0];
            short8 pa0 = lds_read8(pr + g * 8);
            short8 pa1 = lds_read8(pr + 32 + g * 8);
#pragma unroll
            for (int nt = 0; nt < 4; ++nt) {
                int d = nt * 16 + c16;
                const unsigned short* vp = Vh + (size_t)d * 784 + k0 + g * 8;
                short8 v0 = *(const short8*)vp;
                short8 v1 = *(const short8*)(vp + 32);
                o[u][nt] = MFMA16(pa0, v0, o[u][nt]);
                o[u][nt] = MFMA16(pa1, v1, o[u][nt]);
            }
        }
    }

    // normalize and store
#pragma unroll
    for (int u = 0; u < 2; ++u)
#pragma unroll
        for (int r = 0; r < 4; ++r) {
            float lv = l[u][r];
            lv += __shfl_xor(lv, 1);
            lv += __shfl_xor(lv, 2);
            lv += __shfl_xor(lv, 4);
            lv += __shfl_xor(lv, 8);
            l[u][r] = 1.0f / lv;
        }
#pragma unroll
    for (int u = 0; u < 2; ++u)
#pragma unroll
        for (int r = 0; r < 4; ++r) {
            int row = q0 + u * 16 + g * 4 + r;
            if (row < 784) {
#pragma unroll
                for (int nt = 0; nt < 4; ++nt)
                    ctx[(size_t)(b * 784 + row) * 512 + h * 64 + nt * 16 + c16] =
                        f2bf(o[u][nt][r] * l[u][r]);
            }
        }
}

extern "C" void kernel_launch(void* const* d_in, const int* in_sizes, int n_in,
                              void* d_out, int out_size, void* d_ws, size_t ws_size,
                              hipStream_t stream) {
    (void)in_sizes; (void)n_in; (void)out_size; (void)ws_size;
    const float* queries = (const float*)d_in[0];
    const float* keys    = (const float*)d_in[1];
    const float* values  = (const float*)d_in[2];
    const float* corr    = (const float*)d_in[3];
    const float* Wq = (const float*)d_in[4];
    const float* bq = (const float*)d_in[5];
    const float* Wk = (const float*)d_in[6];
    const float* bk = (const float*)d_in[7];
    const float* Wv = (const float*)d_in[8];
    const float* bv = (const float*)d_in[9];
    const float* Wo = (const float*)d_in[10];
    const float* bo = (const float*)d_in[11];

    // workspace: Qb, Kb, Vtb, ctx (bf16, SZX each) + Wt (4 x WSEG bf16) = 53.5 MB
    unsigned short* Qb  = (unsigned short*)d_ws;
    unsigned short* Kb  = Qb + SZX;
    unsigned short* Vtb = Kb + SZX;
    unsigned short* ctx = Vtb + SZX;
    unsigned short* Wt  = ctx + SZX;

    transpose_cvt<<<dim3(16, 16, 4), dim3(32, 8), 0, stream>>>(Wq, Wk, Wv, Wo, Wt);
    gemm_qkv<<<dim3(392, 1, 3), 256, 0, stream>>>(queries, keys, values, Wt,
                                                  bq, bk, bv, Qb, Kb, Vtb);
    attn_kernel<<<dim3(16, 25, 2), 256, 0, stream>>>(Qb, Kb, Vtb, corr, ctx);
    gemm_out<<<dim3(392), 256, 0, stream>>>(Wt + 3 * WSEG, ctx, bo, (float*)d_out);
}